// Round 3
// baseline (75.473 us; speedup 1.0000x reference)
//
#include <hip/hip_runtime.h>

#define BIGF 1e10f
#define HH 256
#define WW 256
#define BB 4
#define NPIX (BB * HH * WW)
#define GRID 256            // == #CUs: 1 block/CU (launch_bounds 1024,4)
#define NBINS 8
#define ACC_STRIDE 8        // doubles: 64 B apart -> distinct L2 lines
#define MAGIC 0x5F3A9C71u   // multi-byte value: cannot alias a byte-pattern ws poison

// ws layout (bytes):
//   [0 .. 511]      double acc bins, one per 64 B
//   [512 .. 515]    unsigned done-counter
//   [768 .. 771]    unsigned init-flag (acc/cnt zeroed & visible)
#define WS_ACC_OFF 0
#define WS_CNT_OFF 512
#define WS_INIT_OFF 768

#define LOAD_RLX(p)     __hip_atomic_load((p), __ATOMIC_RELAXED, __HIP_MEMORY_SCOPE_AGENT)
#define STORE_RLX(p, v) __hip_atomic_store((p), (v), __ATOMIC_RELAXED, __HIP_MEMORY_SCOPE_AGENT)

// Exact 1D distance^2 along a row to the nearest bit of class (mask ^ iv),
// from position x. 8 u32 words per row in LDS; near-uniform addresses per wave.
__device__ inline float row_d2(const unsigned* __restrict__ rm, int x, unsigned iv) {
    int wx = x >> 5, bx = x & 31;
    int dl = 1 << 20, dr = 1 << 20;
    unsigned m0 = rm[wx] ^ iv;                    // shared by both directions
    unsigned t = m0 & (0xFFFFFFFFu >> (31 - bx)); // bits <= bx
    int w = wx;
    while (true) {
        if (t) { int p = (w << 5) + 31 - __builtin_clz(t); dl = x - p; break; }
        if (--w < 0) break;
        t = rm[w] ^ iv;
    }
    t = m0 & (0xFFFFFFFFu << bx);                 // bits >= bx
    w = wx;
    while (true) {
        if (t) { int p = (w << 5) + __builtin_ctz(t); dr = p - x; break; }
        if (++w > 7) break;
        t = rm[w] ^ iv;
    }
    int d = dl < dr ? dl : dr;
    return (d > 255) ? BIGF : (float)(d * d);
}

// Exact expanding-window min-plus along the column; candidate rows' row-dist^2
// computed on demand by bit scan. Skipped candidates satisfy fl(f+s^2) >= s^2 >= best.
__device__ inline float col_min(const unsigned* __restrict__ mb, int y, int x, unsigned iv) {
    float best = row_d2(mb + y * 8, x, iv);
    #pragma unroll 1
    for (int s = 1; s < HH; ++s) {
        float ss = (float)(s * s);
        if (ss >= best) break;
        int ym = y - s, yp = y + s;
        if (ym >= 0) best = fminf(best, row_d2(mb + ym * 8, x, iv) + ss);
        if (yp < HH) best = fminf(best, row_d2(mb + yp * 8, x, iv) + ss);
    }
    return best;
}

// Self-sufficient fused kernel: NO inter-block mask handshake. Each block
// ballots its batch's full pred+tgt images (512 KB, L2-resident: 256 blocks
// read 128 MB from L2 at ~34.5 TB/s ~ 3.7 us, wave-parallel) directly into
// its own LDS masks. Only cross-block state: 8 acc bins + cnt, gated by an
// init-flag block 0 raises at ENTRY (one-shot poll, off critical path).
// No block ever waits on another block's work => no co-residency requirement.
__launch_bounds__(1024, 4)
__global__ void hdt_kernel(const float* __restrict__ pred,
                           const float* __restrict__ tgt,
                           double* __restrict__ acc,
                           unsigned* __restrict__ cnt,
                           unsigned* __restrict__ initf,
                           float* __restrict__ out) {
    int blk = blockIdx.x;          // b*64 + 4-row output tile
    int b = blk >> 6;
    int tid = threadIdx.x;
    int w = tid >> 6, lane = tid & 63;

    __shared__ __align__(16) unsigned lmask[2][HH][8];   // 16 KB
    __shared__ unsigned wfl[16];
    __shared__ float wsum[16];

    if (blk == 0 && tid == 0) {    // init FIRST: visible long before any block's
        #pragma unroll             // end-of-kernel atomics
        for (int i = 0; i < NBINS; ++i) STORE_RLX(&acc[i * ACC_STRIDE], 0.0);
        STORE_RLX(cnt, 0u);
        asm volatile("s_waitcnt vmcnt(0)" ::: "memory");  // zeros ACKed at coherence pt
        STORE_RLX(initf, MAGIC);
    }

    // ---- Phase 1: wave w builds 32 rows of the combined [2][256] row space.
    // Waves 0-7: pred rows, 8-15: tgt rows. Per row: 4 coalesced dword loads +
    // 4 ballots; lane 0 stores 32 B to LDS. fg-any folded from ballot scalars.
    {
        int img = w >> 3;
        const float* base = (img ? tgt : pred) + (b * HH) * WW;
        unsigned any = 0u;
        #pragma unroll 2
        for (int r = 0; r < 32; ++r) {
            int y = ((w & 7) << 5) + r;
            const float* src = base + y * WW + lane;
            unsigned wds[8];
            #pragma unroll
            for (int q = 0; q < 4; ++q) {
                unsigned long long bal = __ballot(src[q << 6] > 0.5f);
                wds[2 * q] = (unsigned)bal;
                wds[2 * q + 1] = (unsigned)(bal >> 32);
                any |= wds[2 * q] | wds[2 * q + 1];
            }
            if (lane == 0) {
                uint4* dst = (uint4*)&lmask[img][y][0];
                dst[0] = make_uint4(wds[0], wds[1], wds[2], wds[3]);
                dst[1] = make_uint4(wds[4], wds[5], wds[6], wds[7]);
            }
        }
        if (lane == 0) wfl[w] = (any != 0u) ? 1u : 0u;   // wave-uniform scalar
    }
    __syncthreads();
    unsigned fl_p = wfl[0] | wfl[1] | wfl[2] | wfl[3] | wfl[4] | wfl[5] | wfl[6] | wfl[7];
    unsigned fl_t = wfl[8] | wfl[9] | wfl[10] | wfl[11] | wfl[12] | wfl[13] | wfl[14] | wfl[15];

    // ---- Phase 2: fused loss over this block's 4-row tile (1 px/thread).
    int x = tid & (WW - 1);
    int y = ((blk & 63) << 2) + (tid >> 8);   // wave-uniform row
    int idx = (b * HH + y) * WW + x;
    float pv = pred[idx], tv = tgt[idx];      // L2-warm: block just read them
    float e = pv - tv;
    float errsq = e * e;
    float d2p = 0.0f, d2t = 0.0f;
    if (fl_p) {
        // query class fg -> scan for bg (invert); bg -> scan for fg
        unsigned iv = (pv > 0.5f) ? 0xFFFFFFFFu : 0u;
        float best = col_min(&lmask[0][0][0], y, x, iv);
        float dt = sqrtf(fminf(best, BIGF));  // match reference: sqrt then square
        d2p = dt * dt;
    }
    if (fl_t) {
        unsigned iv = (tv > 0.5f) ? 0xFFFFFFFFu : 0u;
        float best = col_min(&lmask[1][0][0], y, x, iv);
        float dt = sqrtf(fminf(best, BIGF));
        d2t = dt * dt;
    }
    float lsum = errsq * (d2p + d2t);

    // block reduce: wave64 shuffle then LDS across 16 waves
    #pragma unroll
    for (int off = 32; off > 0; off >>= 1)
        lsum += __shfl_down(lsum, off, 64);
    if ((tid & 63) == 0) wsum[tid >> 6] = lsum;
    __syncthreads();
    if (tid == 0) {
        float s2 = 0.0f;
        #pragma unroll
        for (int i = 0; i < 16; ++i) s2 += wsum[i];
        // one-shot gate: init raised at blk0 entry, ~always already visible
        while (LOAD_RLX(initf) != MAGIC)
            __builtin_amdgcn_s_sleep(2);
        atomicAdd(&acc[(blk & (NBINS - 1)) * ACC_STRIDE], (double)s2);
        // order acc-add before cnt-add without __threadfence (wbl2+inv on gfx950):
        asm volatile("s_waitcnt vmcnt(0)" ::: "memory");
        if (atomicAdd(cnt, 1u) == GRID - 1) {
            double v = 0.0;
            #pragma unroll
            for (int i = 0; i < NBINS; ++i)
                v += atomicAdd(&acc[i * ACC_STRIDE], 0.0);  // coherence-point reads
            out[0] = (float)(v * (1.0 / (double)NPIX));
        }
    }
}

extern "C" void kernel_launch(void* const* d_in, const int* in_sizes, int n_in,
                              void* d_out, int out_size, void* d_ws, size_t ws_size,
                              hipStream_t stream) {
    const float* pred = (const float*)d_in[0];
    const float* tgt = (const float*)d_in[1];
    float* out = (float*)d_out;
    char* ws = (char*)d_ws;
    double* acc = (double*)(ws + WS_ACC_OFF);
    unsigned* cnt = (unsigned*)(ws + WS_CNT_OFF);
    unsigned* initf = (unsigned*)(ws + WS_INIT_OFF);

    hdt_kernel<<<GRID, 1024, 0, stream>>>(pred, tgt, acc, cnt, initf, out);
}

// Round 4
// 72.726 us; speedup vs baseline: 1.0378x; 1.0378x over previous
//
#include <hip/hip_runtime.h>

#define BIGF 1e10f
#define HH 256
#define WW 256
#define BB 4
#define NPIX (BB * HH * WW)
#define GRID 256            // == #CUs: 1 block/CU (launch_bounds 1024,4)
#define MAGIC 0x5F3A9C71u   // multi-byte value: cannot alias a byte-pattern ws poison

// ws layout (bytes):
//   [0 .. 2047]     u64 accb[256] : per-block double partial sums (bit pattern)
//   [2048 .. 3071]  u32 flag[256] : per-block done flags (MAGIC)
// NO workspace init needed: accb is read only after flag==MAGIC.
#define WS_ACCB_OFF 0
#define WS_FLAG_OFF 2048

#define LOAD_RLX(p)     __hip_atomic_load((p), __ATOMIC_RELAXED, __HIP_MEMORY_SCOPE_AGENT)
#define STORE_RLX(p, v) __hip_atomic_store((p), (v), __ATOMIC_RELAXED, __HIP_MEMORY_SCOPE_AGENT)

// Exact 1D distance^2 along a row to the nearest bit of class (mask ^ iv),
// from position x. 8 u32 words per row in LDS; near-uniform addresses per wave.
__device__ inline float row_d2(const unsigned* __restrict__ rm, int x, unsigned iv) {
    int wx = x >> 5, bx = x & 31;
    int dl = 1 << 20, dr = 1 << 20;
    unsigned m0 = rm[wx] ^ iv;                    // shared by both directions
    unsigned t = m0 & (0xFFFFFFFFu >> (31 - bx)); // bits <= bx
    int w = wx;
    while (true) {
        if (t) { int p = (w << 5) + 31 - __builtin_clz(t); dl = x - p; break; }
        if (--w < 0) break;
        t = rm[w] ^ iv;
    }
    t = m0 & (0xFFFFFFFFu << bx);                 // bits >= bx
    w = wx;
    while (true) {
        if (t) { int p = (w << 5) + __builtin_ctz(t); dr = p - x; break; }
        if (++w > 7) break;
        t = rm[w] ^ iv;
    }
    int d = dl < dr ? dl : dr;
    return (d > 255) ? BIGF : (float)(d * d);
}

// Exact expanding-window min-plus along the column; candidate rows' row-dist^2
// computed on demand by bit scan. Skipped candidates satisfy fl(f+s^2) >= s^2 >= best.
__device__ inline float col_min(const unsigned* __restrict__ mb, int y, int x, unsigned iv) {
    float best = row_d2(mb + y * 8, x, iv);
    #pragma unroll 1
    for (int s = 1; s < HH; ++s) {
        float ss = (float)(s * s);
        if (ss >= best) break;
        int ym = y - s, yp = y + s;
        if (ym >= 0) best = fminf(best, row_d2(mb + ym * 8, x, iv) + ss);
        if (yp < HH) best = fminf(best, row_d2(mb + yp * 8, x, iv) + ss);
    }
    return best;
}

// Self-sufficient fused kernel, v2:
//  - build: float4 loads (16 B/lane) + nibble pack + 3-step shfl_xor OR-tree;
//    32 loads/wave instead of 128, no ballots -> cuts the serial-latency chain
//    that cost round 3 ~7 us.
//  - tail: zero atomics. Block k stores its double partial + raises flag[k];
//    block 0 polls 256 flags (1/thread), tree-reduces, writes out.
//    No workspace init, no init gate, no serialized MALL RMW chain.
__launch_bounds__(1024, 4)
__global__ void hdt_kernel(const float* __restrict__ pred,
                           const float* __restrict__ tgt,
                           unsigned long long* __restrict__ accb,
                           unsigned* __restrict__ flag,
                           float* __restrict__ out) {
    int blk = blockIdx.x;          // b*64 + 4-row output tile
    int b = blk >> 6;
    int tid = threadIdx.x;
    int w = tid >> 6, lane = tid & 63;

    __shared__ __align__(16) unsigned lmask[2][HH][8];   // 16 KB
    __shared__ unsigned wfl[16];
    __shared__ float wsum[16];
    __shared__ double dsum[4];

    // prefetch this thread's pixel pair: HBM/L2 latency hides under the build
    int x = tid & (WW - 1);
    int yq = ((blk & 63) << 2) + (tid >> 8);  // wave-uniform row of the 4-row tile
    int idx = (b * HH + yq) * WW + x;
    float pv = pred[idx], tv = tgt[idx];

    // ---- Phase 1: wave w builds 32 rows (waves 0-7: pred, 8-15: tgt).
    // Lane L covers pixels [4L,4L+4) of the row: float4 load -> 4-bit nibble at
    // bit 4*(L&7); OR-tree over lanes L^1,L^2,L^4 assembles word (L>>3); the 8
    // lanes with (L&7)==0 store words 0..7 (bank-distinct ds_write_b32).
    {
        int img = w >> 3;
        const float* base = (img ? tgt : pred) + (b * HH) * WW;
        unsigned any = 0u;
        #pragma unroll 4
        for (int r = 0; r < 32; ++r) {
            int y = ((w & 7) << 5) + r;
            const float4 f = ((const float4*)(base + y * WW))[lane];
            unsigned nib = (f.x > 0.5f ? 1u : 0u) | (f.y > 0.5f ? 2u : 0u)
                         | (f.z > 0.5f ? 4u : 0u) | (f.w > 0.5f ? 8u : 0u);
            unsigned v = nib << ((lane & 7) << 2);
            v |= __shfl_xor(v, 1, 64);
            v |= __shfl_xor(v, 2, 64);
            v |= __shfl_xor(v, 4, 64);   // all 8 lanes of a group now hold the word
            any |= v;
            if ((lane & 7) == 0) lmask[img][y][lane >> 3] = v;
        }
        unsigned long long ab = __ballot(any != 0u);     // one ballot per wave total
        if (lane == 0) wfl[w] = (ab != 0ULL) ? 1u : 0u;
    }
    __syncthreads();
    unsigned fl_p = wfl[0] | wfl[1] | wfl[2] | wfl[3] | wfl[4] | wfl[5] | wfl[6] | wfl[7];
    unsigned fl_t = wfl[8] | wfl[9] | wfl[10] | wfl[11] | wfl[12] | wfl[13] | wfl[14] | wfl[15];

    // ---- Phase 2: fused loss over this block's 4-row tile (1 px/thread).
    float e = pv - tv;
    float errsq = e * e;
    float d2p = 0.0f, d2t = 0.0f;
    if (fl_p) {
        // query class fg -> scan for bg (invert); bg -> scan for fg
        unsigned iv = (pv > 0.5f) ? 0xFFFFFFFFu : 0u;
        float best = col_min(&lmask[0][0][0], yq, x, iv);
        float dt = sqrtf(fminf(best, BIGF));  // match reference: sqrt then square
        d2p = dt * dt;
    }
    if (fl_t) {
        unsigned iv = (tv > 0.5f) ? 0xFFFFFFFFu : 0u;
        float best = col_min(&lmask[1][0][0], yq, x, iv);
        float dt = sqrtf(fminf(best, BIGF));
        d2t = dt * dt;
    }
    float lsum = errsq * (d2p + d2t);

    // block reduce: wave64 shuffle then LDS across 16 waves
    #pragma unroll
    for (int off = 32; off > 0; off >>= 1)
        lsum += __shfl_down(lsum, off, 64);
    if ((tid & 63) == 0) wsum[tid >> 6] = lsum;
    __syncthreads();
    if (tid == 0) {
        float s2 = 0.0f;
        #pragma unroll
        for (int i = 0; i < 16; ++i) s2 += wsum[i];
        STORE_RLX(&accb[blk], (unsigned long long)__double_as_longlong((double)s2));
        // drain the partial-sum store to the coherence point BEFORE the flag:
        asm volatile("s_waitcnt vmcnt(0)" ::: "memory");
        STORE_RLX(&flag[blk], MAGIC);
    }

    // ---- Finalize (block 0 only): poll 256 flags (1/thread), tree-reduce the
    // 256 double partials, write out. Block 0 waits only on others' *completed*
    // work; no block ever waits on block 0 -> no co-residency requirement.
    if (blk == 0) {
        double v = 0.0;
        if (tid < GRID) {
            while (LOAD_RLX(&flag[tid]) != MAGIC)
                __builtin_amdgcn_s_sleep(2);
            v = __longlong_as_double((long long)LOAD_RLX(&accb[tid]));
        }
        #pragma unroll
        for (int off = 32; off > 0; off >>= 1)
            v += __shfl_down(v, off, 64);
        if (tid < GRID && (tid & 63) == 0) dsum[tid >> 6] = v;
        __syncthreads();
        if (tid == 0)
            out[0] = (float)((dsum[0] + dsum[1] + dsum[2] + dsum[3])
                             * (1.0 / (double)NPIX));
    }
}

extern "C" void kernel_launch(void* const* d_in, const int* in_sizes, int n_in,
                              void* d_out, int out_size, void* d_ws, size_t ws_size,
                              hipStream_t stream) {
    const float* pred = (const float*)d_in[0];
    const float* tgt = (const float*)d_in[1];
    float* out = (float*)d_out;
    char* ws = (char*)d_ws;
    unsigned long long* accb = (unsigned long long*)(ws + WS_ACCB_OFF);
    unsigned* flag = (unsigned*)(ws + WS_FLAG_OFF);

    hdt_kernel<<<GRID, 1024, 0, stream>>>(pred, tgt, accb, flag, out);
}

// Round 5
// 63.872 us; speedup vs baseline: 1.1816x; 1.1386x over previous
//
#include <hip/hip_runtime.h>

#define BIGF 1e10f
#define HH 256
#define WW 256
#define BB 4
#define NPIX (BB * HH * WW)
#define GRID 256            // == #CUs: 1 block/CU (launch_bounds 1024,4)
#define MAGIC 0x5F3A9C71u   // multi-byte value: cannot alias a byte-pattern ws poison

// ws layout (bytes):
//   [0 .. 2047]     u64 accb[256] : per-block double partial sums (bit pattern)
//   [2048 .. 3071]  u32 ready[256] : producer mask-publish flags
//   [3072 .. 4095]  u32 done[256]  : partial-sum-published flags
//   [4096 .. +64K)  u32 gmask[2][BB][HH][8] : fg bit-masks, bit x of row y
// NO workspace init needed: accb/gmask are read only after their flag==MAGIC.
#define WS_ACCB_OFF 0
#define WS_RDY_OFF 2048
#define WS_DONE_OFF 3072
#define WS_MASK_OFF 4096

#define LOAD_RLX(p)     __hip_atomic_load((p), __ATOMIC_RELAXED, __HIP_MEMORY_SCOPE_AGENT)
#define STORE_RLX(p, v) __hip_atomic_store((p), (v), __ATOMIC_RELAXED, __HIP_MEMORY_SCOPE_AGENT)

// Exact 1D distance^2 along a row to the nearest bit of class (mask ^ iv),
// from position x. 8 u32 words per row in LDS; near-uniform addresses per wave.
__device__ inline float row_d2(const unsigned* __restrict__ rm, int x, unsigned iv) {
    int wx = x >> 5, bx = x & 31;
    int dl = 1 << 20, dr = 1 << 20;
    unsigned m0 = rm[wx] ^ iv;                    // shared by both directions
    unsigned t = m0 & (0xFFFFFFFFu >> (31 - bx)); // bits <= bx
    int w = wx;
    while (true) {
        if (t) { int p = (w << 5) + 31 - __builtin_clz(t); dl = x - p; break; }
        if (--w < 0) break;
        t = rm[w] ^ iv;
    }
    t = m0 & (0xFFFFFFFFu << bx);                 // bits >= bx
    w = wx;
    while (true) {
        if (t) { int p = (w << 5) + __builtin_ctz(t); dr = p - x; break; }
        if (++w > 7) break;
        t = rm[w] ^ iv;
    }
    int d = dl < dr ? dl : dr;
    return (d > 255) ? BIGF : (float)(d * d);
}

// Exact expanding-window min-plus along the column; candidate rows' row-dist^2
// computed on demand by bit scan. Skipped candidates satisfy fl(f+s^2) >= s^2 >= best.
__device__ inline float col_min(const unsigned* __restrict__ mb, int y, int x, unsigned iv) {
    float best = row_d2(mb + y * 8, x, iv);
    #pragma unroll 1
    for (int s = 1; s < HH; ++s) {
        float ss = (float)(s * s);
        if (ss >= best) break;
        int ym = y - s, yp = y + s;
        if (ym >= 0) best = fminf(best, row_d2(mb + ym * 8, x, iv) + ss);
        if (yp < HH) best = fminf(best, row_d2(mb + yp * 8, x, iv) + ss);
    }
    return best;
}

// Round-2 structure (best measured: tiny producers + relaxed-sc1 handshake,
// no cache-maintenance ops) with three surgical changes:
//  1. gate polls only the 64 producer flags of this block's own batch
//  2. atomic-free tail: store partial + done-flag; block 0 reduces
//  3. query pixels prefetched before phase 1
__launch_bounds__(1024, 4)
__global__ void hdt_kernel(const float* __restrict__ pred,
                           const float* __restrict__ tgt,
                           unsigned* __restrict__ gmask,
                           unsigned* __restrict__ ready,
                           unsigned* __restrict__ done,
                           unsigned long long* __restrict__ accb,
                           float* __restrict__ out) {
    int blk = blockIdx.x;          // b*64 + tile index
    int b = blk >> 6;
    int tid = threadIdx.x;
    int w = tid >> 6, lane = tid & 63;

    __shared__ __align__(16) unsigned lmask[2][HH][8];   // 16 KB
    __shared__ unsigned wfl[16];
    __shared__ float wsum[16];
    __shared__ double dsum[4];

    // prefetch this thread's query pixels: latency hides under build+handshake
    int x = tid & (WW - 1);
    int yq = ((blk & 63) << 2) + (tid >> 8);  // wave-uniform row of the 4-row tile
    int idx = (b * HH + yq) * WW + x;
    float pv = pred[idx], tv = tgt[idx];

    // ---- Phase 1: build 8 of this batch's 512 mask rows (2 imgs x 256 rows).
    // Wave w: row (blk&63)*8 + (w>>1), half (w&1). 2 coalesced loads + 2 ballots,
    // lane 0 publishes the two ballot u64s write-through (sc1, no maintenance).
    {
        int r = ((blk & 63) << 3) + (w >> 1);   // row within batch: 0..511
        int img = r >> 8, y = r & 255, half = w & 1;
        const float* src = (img ? tgt : pred) + (b * HH + y) * WW + half * 128 + lane;
        unsigned long long b0 = __ballot(src[0] > 0.5f);
        unsigned long long b1 = __ballot(src[64] > 0.5f);
        if (lane == 0) {
            unsigned long long* dst = (unsigned long long*)
                (gmask + ((img * BB + b) * HH + y) * 8 + half * 4);
            STORE_RLX(dst, b0);       // words {0,1} of the half-row
            STORE_RLX(dst + 1, b1);   // words {2,3}
        }
    }
    __syncthreads();                  // s_waitcnt vmcnt(0): all sc1 stores ACKed
    if (tid == 0) STORE_RLX(&ready[blk], MAGIC);   // relaxed publish: no wbl2

    // ---- Gate: wave 0 polls the 64 producer flags of THIS batch only
    // (decouples the four batch groups' dispatch stragglers).
    if (tid < 64) {
        while (LOAD_RLX(&ready[(b << 6) + tid]) != MAGIC)
            __builtin_amdgcn_s_sleep(2);
    }
    __syncthreads();

    // ---- Phase 2: stage this batch's masks (2 x u64 sc1 loads/thread, linear
    // LDS order), empty-fg flags from staged words, fused loss + block reduce.
    {
        int img = tid >> 9;
        int row = (tid >> 1) & 255;
        int half = tid & 1;
        const unsigned long long* gp = (const unsigned long long*)
            (gmask + ((img * BB + b) * HH + row) * 8 + half * 4);
        unsigned long long v0 = LOAD_RLX(gp);
        unsigned long long v1 = LOAD_RLX(gp + 1);
        uint4 a = make_uint4((unsigned)v0, (unsigned)(v0 >> 32),
                             (unsigned)v1, (unsigned)(v1 >> 32));
        ((uint4*)lmask)[tid] = a;
        unsigned onz = a.x | a.y | a.z | a.w;
        unsigned long long bal = __ballot(onz != 0u);    // waves 0-7: img0, 8-15: img1
        if ((tid & 63) == 0) wfl[tid >> 6] = (bal != 0ULL) ? 1u : 0u;
    }
    __syncthreads();
    unsigned fl_p = wfl[0] | wfl[1] | wfl[2] | wfl[3] | wfl[4] | wfl[5] | wfl[6] | wfl[7];
    unsigned fl_t = wfl[8] | wfl[9] | wfl[10] | wfl[11] | wfl[12] | wfl[13] | wfl[14] | wfl[15];

    float e = pv - tv;
    float errsq = e * e;
    float d2p = 0.0f, d2t = 0.0f;
    if (fl_p) {
        // query class fg -> scan for bg (invert); bg -> scan for fg
        unsigned iv = (pv > 0.5f) ? 0xFFFFFFFFu : 0u;
        float best = col_min(&lmask[0][0][0], yq, x, iv);
        float dt = sqrtf(fminf(best, BIGF));  // match reference: sqrt then square
        d2p = dt * dt;
    }
    if (fl_t) {
        unsigned iv = (tv > 0.5f) ? 0xFFFFFFFFu : 0u;
        float best = col_min(&lmask[1][0][0], yq, x, iv);
        float dt = sqrtf(fminf(best, BIGF));
        d2t = dt * dt;
    }
    float lsum = errsq * (d2p + d2t);

    // block reduce: wave64 shuffle then LDS across 16 waves
    #pragma unroll
    for (int off = 32; off > 0; off >>= 1)
        lsum += __shfl_down(lsum, off, 64);
    if ((tid & 63) == 0) wsum[tid >> 6] = lsum;
    __syncthreads();

    // ---- Atomic-free tail: publish partial, then block 0 reduces all 256.
    if (tid == 0) {
        float s2 = 0.0f;
        #pragma unroll
        for (int i = 0; i < 16; ++i) s2 += wsum[i];
        STORE_RLX(&accb[blk], (unsigned long long)__double_as_longlong((double)s2));
        asm volatile("s_waitcnt vmcnt(0)" ::: "memory");  // partial ACKed before flag
        STORE_RLX(&done[blk], MAGIC);
    }
    if (blk == 0) {   // waits only on others' COMPLETED work; nobody waits on blk 0
        double v = 0.0;
        if (tid < GRID) {
            while (LOAD_RLX(&done[tid]) != MAGIC)
                __builtin_amdgcn_s_sleep(2);
            v = __longlong_as_double((long long)LOAD_RLX(&accb[tid]));
        }
        #pragma unroll
        for (int off = 32; off > 0; off >>= 1)
            v += __shfl_down(v, off, 64);
        if (tid < GRID && (tid & 63) == 0) dsum[tid >> 6] = v;
        __syncthreads();
        if (tid == 0)
            out[0] = (float)((dsum[0] + dsum[1] + dsum[2] + dsum[3])
                             * (1.0 / (double)NPIX));
    }
}

extern "C" void kernel_launch(void* const* d_in, const int* in_sizes, int n_in,
                              void* d_out, int out_size, void* d_ws, size_t ws_size,
                              hipStream_t stream) {
    const float* pred = (const float*)d_in[0];
    const float* tgt = (const float*)d_in[1];
    float* out = (float*)d_out;
    char* ws = (char*)d_ws;
    unsigned long long* accb = (unsigned long long*)(ws + WS_ACCB_OFF);
    unsigned* ready = (unsigned*)(ws + WS_RDY_OFF);
    unsigned* done = (unsigned*)(ws + WS_DONE_OFF);
    unsigned* gmask = (unsigned*)(ws + WS_MASK_OFF);

    hdt_kernel<<<GRID, 1024, 0, stream>>>(pred, tgt, gmask, ready, done, accb, out);
}

// Round 7
// 62.809 us; speedup vs baseline: 1.2016x; 1.0169x over previous
//
#include <hip/hip_runtime.h>

#define BIGF 1e10f
#define HH 256
#define WW 256
#define BB 4
#define NPIX (BB * HH * WW)
#define GRID 256            // == #CUs: 1 block/CU
#define MAGIC 0x5F3A9C71u   // multi-byte value: cannot alias a byte-pattern ws poison
#define SMAX 16             // local column window; exact iff best <= (SMAX+1)^2
#define CONV_T 289.0f       // (SMAX+1)^2

// ws layout (bytes):
//   [0 .. 2047]     u64 accb[256] : per-block double partial sums (bit pattern)
//   [2048 .. 3071]  u32 ready[256] : producer mask-publish flags
//   [3072 .. 4095]  u32 done[256]  : partial-sum-published flags
//   [4096 .. +64K)  u32 gmask[2][BB][HH][8] : fg bit-masks, bit x of row y
// NO workspace init needed: accb/gmask are read only after their flag==MAGIC.
#define WS_ACCB_OFF 0
#define WS_RDY_OFF 2048
#define WS_DONE_OFF 3072
#define WS_MASK_OFF 4096

#define LOAD_RLX(p)     __hip_atomic_load((p), __ATOMIC_RELAXED, __HIP_MEMORY_SCOPE_AGENT)
#define STORE_RLX(p, v) __hip_atomic_store((p), (v), __ATOMIC_RELAXED, __HIP_MEMORY_SCOPE_AGENT)

// Exact 1D distance^2 along a row to the nearest bit of class (mask ^ iv),
// from position x. 8 u32 words per row in LDS; near-uniform addresses per wave.
__device__ inline float row_d2(const unsigned* __restrict__ rm, int x, unsigned iv) {
    int wx = x >> 5, bx = x & 31;
    int dl = 1 << 20, dr = 1 << 20;
    unsigned m0 = rm[wx] ^ iv;                    // shared by both directions
    unsigned t = m0 & (0xFFFFFFFFu >> (31 - bx)); // bits <= bx
    int w = wx;
    while (true) {
        if (t) { int p = (w << 5) + 31 - __builtin_clz(t); dl = x - p; break; }
        if (--w < 0) break;
        t = rm[w] ^ iv;
    }
    t = m0 & (0xFFFFFFFFu << bx);                 // bits >= bx
    w = wx;
    while (true) {
        if (t) { int p = (w << 5) + __builtin_ctz(t); dr = p - x; break; }
        if (++w > 7) break;
        t = rm[w] ^ iv;
    }
    int d = dl < dr ? dl : dr;
    return (d > 255) ? BIGF : (float)(d * d);
}

// Exact expanding-window min-plus along the column (full range, fallback path).
__device__ inline float col_min(const unsigned* __restrict__ mb, int y, int x, unsigned iv) {
    float best = row_d2(mb + y * 8, x, iv);
    #pragma unroll 1
    for (int s = 1; s < HH; ++s) {
        float ss = (float)(s * s);
        if (ss >= best) break;
        int ym = y - s, yp = y + s;
        if (ym >= 0) best = fminf(best, row_d2(mb + ym * 8, x, iv) + ss);
        if (yp < HH) best = fminf(best, row_d2(mb + yp * 8, x, iv) + ss);
    }
    return best;
}

// Truncated variant: identical iterations while s <= SMAX. Result equals the
// full loop's iff best <= (SMAX+1)^2 (caller checks; farther candidates >= that).
__device__ inline float col_min_win(const unsigned* __restrict__ mb, int y, int x, unsigned iv) {
    float best = row_d2(mb + y * 8, x, iv);
    #pragma unroll 1
    for (int s = 1; s <= SMAX; ++s) {
        float ss = (float)(s * s);
        if (ss >= best) break;
        int ym = y - s, yp = y + s;
        if (ym >= 0) best = fminf(best, row_d2(mb + ym * 8, x, iv) + ss);
        if (yp < HH) best = fminf(best, row_d2(mb + yp * 8, x, iv) + ss);
    }
    return best;
}

// Round-5 structure with the handshake moved OFF the common critical path:
// each block locally builds the +-SMAX-row neighborhood of its tile (float4 +
// shfl_xor OR-tree) and computes the truncated col_min; a converged query
// (best <= (SMAX+1)^2) is exact and implies fg-any=1. Only if some thread
// fails to converge (sparse/empty masks -- not this data) does the block poll
// the always-published global masks and recompute. Atomic-free tail as before.
__launch_bounds__(1024, 4)
__global__ void hdt_kernel(const float* __restrict__ pred,
                           const float* __restrict__ tgt,
                           unsigned* __restrict__ gmask,
                           unsigned* __restrict__ ready,
                           unsigned* __restrict__ done,
                           unsigned long long* __restrict__ accb,
                           float* __restrict__ out) {
    int blk = blockIdx.x;          // b*64 + tile index
    int b = blk >> 6;
    int tid = threadIdx.x;
    int w = tid >> 6, lane = tid & 63;

    __shared__ __align__(16) unsigned lmask[2][HH][8];   // 16 KB (full, for fallback)
    __shared__ unsigned wfl[16];
    __shared__ float wsum[16];
    __shared__ double dsum[4];

    // prefetch this thread's query pixels: latency hides under the build
    int x = tid & (WW - 1);
    int y0 = (blk & 63) << 2;
    int yq = y0 + (tid >> 8);                 // wave-uniform row of the 4-row tile
    int idx = (b * HH + yq) * WW + x;
    float pv = pred[idx], tv = tgt[idx];

    // ---- Publish (always; consumed only on fallback): wave w ballots half-row
    // r=(blk&63)*8+(w>>1), half (w&1): 2 coalesced loads + 2 ballots, sc1 stores.
    {
        int r = ((blk & 63) << 3) + (w >> 1);   // row within batch: 0..511
        int img = r >> 8, y = r & 255, half = w & 1;
        const float* src = (img ? tgt : pred) + (b * HH + y) * WW + half * 128 + lane;
        unsigned long long b0 = __ballot(src[0] > 0.5f);
        unsigned long long b1 = __ballot(src[64] > 0.5f);
        if (lane == 0) {
            unsigned long long* dst = (unsigned long long*)
                (gmask + ((img * BB + b) * HH + y) * 8 + half * 4);
            STORE_RLX(dst, b0);
            STORE_RLX(dst + 1, b1);
        }
    }

    // ---- Local window build: rows [y0-SMAX, y0+3+SMAX] clamped, both images.
    // One row per wave-iteration: float4/lane + nibble pack + 3-step shfl_xor
    // OR-tree; 8 lanes store the row's 8 words. <= 72 rows -> <=5 iters/wave.
    int ylo = y0 - SMAX; if (ylo < 0) ylo = 0;
    int yhi = y0 + 3 + SMAX; if (yhi > HH - 1) yhi = HH - 1;
    int nrows = yhi - ylo + 1;
    int tot = nrows * 2;
    #pragma unroll 2
    for (int i = w; i < tot; i += 16) {
        int img = (i >= nrows) ? 1 : 0;
        int y = ylo + (img ? i - nrows : i);
        const float* rowp = (img ? tgt : pred) + (b * HH + y) * WW;
        const float4 f = ((const float4*)rowp)[lane];
        unsigned nib = (f.x > 0.5f ? 1u : 0u) | (f.y > 0.5f ? 2u : 0u)
                     | (f.z > 0.5f ? 4u : 0u) | (f.w > 0.5f ? 8u : 0u);
        unsigned v = nib << ((lane & 7) << 2);
        v |= __shfl_xor(v, 1, 64);
        v |= __shfl_xor(v, 2, 64);
        v |= __shfl_xor(v, 4, 64);   // all 8 lanes of a group hold the word
        if ((lane & 7) == 0) lmask[img][y][lane >> 3] = v;
    }
    __syncthreads();                  // drains vmcnt(0): publish stores ACKed
    if (tid == 0) STORE_RLX(&ready[blk], MAGIC);

    // ---- Fast path: truncated col_min on the local window.
    unsigned ivp = (pv > 0.5f) ? 0xFFFFFFFFu : 0u;
    unsigned ivt = (tv > 0.5f) ? 0xFFFFFFFFu : 0u;
    float bp = col_min_win(&lmask[0][0][0], yq, x, ivp);
    float bt = col_min_win(&lmask[1][0][0], yq, x, ivt);
    bool conv_p = (bp <= CONV_T), conv_t = (bt <= CONV_T);
    float d2p = 0.0f, d2t = 0.0f;
    if (conv_p) { float dt = sqrtf(fminf(bp, BIGF)); d2p = dt * dt; }
    if (conv_t) { float dt = sqrtf(fminf(bt, BIGF)); d2t = dt * dt; }

    // block-uniform fallback decision
    unsigned long long fb = __ballot(!(conv_p && conv_t));
    if ((tid & 63) == 0) wfl[w] = (fb != 0ULL) ? 1u : 0u;
    __syncthreads();
    unsigned fb_any = wfl[0] | wfl[1] | wfl[2] | wfl[3] | wfl[4] | wfl[5] | wfl[6]
                    | wfl[7] | wfl[8] | wfl[9] | wfl[10] | wfl[11] | wfl[12]
                    | wfl[13] | wfl[14] | wfl[15];

    if (fb_any) {
        // ---- Fallback (pathological masks only): poll batch producers, stage
        // full masks, recompute unconverged threads with fg-any gating.
        __syncthreads();              // everyone done reading wfl before reuse
        if (tid < 64) {
            while (LOAD_RLX(&ready[(b << 6) + tid]) != MAGIC)
                __builtin_amdgcn_s_sleep(2);
        }
        __syncthreads();
        {
            int img = tid >> 9;
            int row = (tid >> 1) & 255;
            int half = tid & 1;
            const unsigned long long* gp = (const unsigned long long*)
                (gmask + ((img * BB + b) * HH + row) * 8 + half * 4);
            unsigned long long v0 = LOAD_RLX(gp);
            unsigned long long v1 = LOAD_RLX(gp + 1);
            uint4 a = make_uint4((unsigned)v0, (unsigned)(v0 >> 32),
                                 (unsigned)v1, (unsigned)(v1 >> 32));
            ((uint4*)lmask)[tid] = a;
            unsigned onz = a.x | a.y | a.z | a.w;
            unsigned long long bal = __ballot(onz != 0u);  // w 0-7: img0, 8-15: img1
            if ((tid & 63) == 0) wfl[tid >> 6] = (bal != 0ULL) ? 1u : 0u;
        }
        __syncthreads();
        unsigned fl_p = wfl[0] | wfl[1] | wfl[2] | wfl[3] | wfl[4] | wfl[5] | wfl[6] | wfl[7];
        unsigned fl_t = wfl[8] | wfl[9] | wfl[10] | wfl[11] | wfl[12] | wfl[13] | wfl[14] | wfl[15];
        if (!conv_p) {
            d2p = 0.0f;
            if (fl_p) {
                float best = col_min(&lmask[0][0][0], yq, x, ivp);
                float dt = sqrtf(fminf(best, BIGF));
                d2p = dt * dt;
            }
        }
        if (!conv_t) {
            d2t = 0.0f;
            if (fl_t) {
                float best = col_min(&lmask[1][0][0], yq, x, ivt);
                float dt = sqrtf(fminf(best, BIGF));
                d2t = dt * dt;
            }
        }
    }

    float e = pv - tv;
    float lsum = (e * e) * (d2p + d2t);

    // block reduce: wave64 shuffle then LDS across 16 waves
    #pragma unroll
    for (int off = 32; off > 0; off >>= 1)
        lsum += __shfl_down(lsum, off, 64);
    if ((tid & 63) == 0) wsum[tid >> 6] = lsum;
    __syncthreads();

    // ---- Atomic-free tail: publish partial, then block 0 reduces all 256.
    if (tid == 0) {
        float s2 = 0.0f;
        #pragma unroll
        for (int i = 0; i < 16; ++i) s2 += wsum[i];
        STORE_RLX(&accb[blk], (unsigned long long)__double_as_longlong((double)s2));
        asm volatile("s_waitcnt vmcnt(0)" ::: "memory");  // partial ACKed before flag
        STORE_RLX(&done[blk], MAGIC);
    }
    if (blk == 0) {   // waits only on others' COMPLETED work; nobody waits on blk 0
        double v = 0.0;
        if (tid < GRID) {
            while (LOAD_RLX(&done[tid]) != MAGIC)
                __builtin_amdgcn_s_sleep(2);
            v = __longlong_as_double((long long)LOAD_RLX(&accb[tid]));
        }
        #pragma unroll
        for (int off = 32; off > 0; off >>= 1)
            v += __shfl_down(v, off, 64);
        if (tid < GRID && (tid & 63) == 0) dsum[tid >> 6] = v;
        __syncthreads();
        if (tid == 0)
            out[0] = (float)((dsum[0] + dsum[1] + dsum[2] + dsum[3])
                             * (1.0 / (double)NPIX));
    }
}

extern "C" void kernel_launch(void* const* d_in, const int* in_sizes, int n_in,
                              void* d_out, int out_size, void* d_ws, size_t ws_size,
                              hipStream_t stream) {
    const float* pred = (const float*)d_in[0];
    const float* tgt = (const float*)d_in[1];
    float* out = (float*)d_out;
    char* ws = (char*)d_ws;
    unsigned long long* accb = (unsigned long long*)(ws + WS_ACCB_OFF);
    unsigned* ready = (unsigned*)(ws + WS_RDY_OFF);
    unsigned* done = (unsigned*)(ws + WS_DONE_OFF);
    unsigned* gmask = (unsigned*)(ws + WS_MASK_OFF);

    hdt_kernel<<<GRID, 1024, 0, stream>>>(pred, tgt, gmask, ready, done, accb, out);
}

// Round 8
// 61.101 us; speedup vs baseline: 1.2352x; 1.0280x over previous
//
#include <hip/hip_runtime.h>

#define BIGF 1e10f
#define HH 256
#define WW 256
#define BB 4
#define NPIX (BB * HH * WW)
#define GRID 256            // == #CUs: 1 block/CU
#define MAGIC 0x5F3A9C71u   // multi-byte value: cannot alias a byte-pattern ws poison
#define SMAX 8              // local column window; exact iff best <= (SMAX+1)^2
#define CONV_T 81.0f        // (SMAX+1)^2

// ws layout (bytes):
//   [0 .. 2047]     u64 accb[256] : per-block double partial sums (bit pattern)
//   [3072 .. 4095]  u32 done[256] : partial-sum-published flags
// NO workspace init needed: accb is read only after done==MAGIC.
#define WS_ACCB_OFF 0
#define WS_DONE_OFF 3072

#define LOAD_RLX(p)     __hip_atomic_load((p), __ATOMIC_RELAXED, __HIP_MEMORY_SCOPE_AGENT)
#define STORE_RLX(p, v) __hip_atomic_store((p), (v), __ATOMIC_RELAXED, __HIP_MEMORY_SCOPE_AGENT)

// Exact 1D distance^2 along a row to the nearest bit of class (mask ^ iv),
// from position x. 8 u32 words per row in LDS; near-uniform addresses per wave.
__device__ inline float row_d2(const unsigned* __restrict__ rm, int x, unsigned iv) {
    int wx = x >> 5, bx = x & 31;
    int dl = 1 << 20, dr = 1 << 20;
    unsigned m0 = rm[wx] ^ iv;                    // shared by both directions
    unsigned t = m0 & (0xFFFFFFFFu >> (31 - bx)); // bits <= bx
    int w = wx;
    while (true) {
        if (t) { int p = (w << 5) + 31 - __builtin_clz(t); dl = x - p; break; }
        if (--w < 0) break;
        t = rm[w] ^ iv;
    }
    t = m0 & (0xFFFFFFFFu << bx);                 // bits >= bx
    w = wx;
    while (true) {
        if (t) { int p = (w << 5) + __builtin_ctz(t); dr = p - x; break; }
        if (++w > 7) break;
        t = rm[w] ^ iv;
    }
    int d = dl < dr ? dl : dr;
    return (d > 255) ? BIGF : (float)(d * d);
}

// Exact expanding-window min-plus along the column (full range, fallback path).
__device__ inline float col_min(const unsigned* __restrict__ mb, int y, int x, unsigned iv) {
    float best = row_d2(mb + y * 8, x, iv);
    #pragma unroll 1
    for (int s = 1; s < HH; ++s) {
        float ss = (float)(s * s);
        if (ss >= best) break;
        int ym = y - s, yp = y + s;
        if (ym >= 0) best = fminf(best, row_d2(mb + ym * 8, x, iv) + ss);
        if (yp < HH) best = fminf(best, row_d2(mb + yp * 8, x, iv) + ss);
    }
    return best;
}

// Fused truncated variant: both images in ONE s-loop (2x ILP on the dependent
// LDS-scan chain). Per-image iterations are identical to the full loop while
// s <= SMAX; result exact iff it converged (best <= (SMAX+1)^2).
__device__ inline void col_min2_win(const unsigned* __restrict__ mb0,
                                    const unsigned* __restrict__ mb1,
                                    int y, int x, unsigned iv0, unsigned iv1,
                                    float& b0, float& b1) {
    b0 = row_d2(mb0 + y * 8, x, iv0);
    b1 = row_d2(mb1 + y * 8, x, iv1);
    #pragma unroll 1
    for (int s = 1; s <= SMAX; ++s) {
        float ss = (float)(s * s);
        bool d0 = (ss >= b0), d1 = (ss >= b1);
        if (d0 && d1) break;
        int ym = y - s, yp = y + s;
        if (!d0) {
            if (ym >= 0) b0 = fminf(b0, row_d2(mb0 + ym * 8, x, iv0) + ss);
            if (yp < HH) b0 = fminf(b0, row_d2(mb0 + yp * 8, x, iv0) + ss);
        }
        if (!d1) {
            if (ym >= 0) b1 = fminf(b1, row_d2(mb1 + ym * 8, x, iv1) + ss);
            if (yp < HH) b1 = fminf(b1, row_d2(mb1 + yp * 8, x, iv1) + ss);
        }
    }
}

// pack one row's 256 pixels into 8 mask words: float4/lane + nibble + shfl OR-tree
#define PACK_ROW(rowp, vout)                                                  \
    {                                                                         \
        const float4 f = ((const float4*)(rowp))[lane];                       \
        unsigned nib = (f.x > 0.5f ? 1u : 0u) | (f.y > 0.5f ? 2u : 0u)        \
                     | (f.z > 0.5f ? 4u : 0u) | (f.w > 0.5f ? 8u : 0u);       \
        vout = nib << ((lane & 7) << 2);                                      \
        vout |= __shfl_xor(vout, 1, 64);                                      \
        vout |= __shfl_xor(vout, 2, 64);                                      \
        vout |= __shfl_xor(vout, 4, 64);                                      \
    }

// Fully self-sufficient kernel: NO inter-block mask traffic at all.
// Fast path: local +-SMAX window build + fused truncated col_min (exact when
// converged; convergence implies fg-any). Rare fallback (sparse/empty masks):
// block rebuilds the FULL 512-row mask set locally and recomputes unconverged
// threads with fg-any gating. Tail: atomic-free store+flag, block 0 reduces.
// XCD-chunked tile map: consecutive tiles (sharing window rows) on one XCD's L2.
__launch_bounds__(1024, 4)
__global__ void hdt_kernel(const float* __restrict__ pred,
                           const float* __restrict__ tgt,
                           unsigned* __restrict__ done,
                           unsigned long long* __restrict__ accb,
                           float* __restrict__ out) {
    // XCD-aware swizzle: blockIdx round-robins XCDs; chunk so logical tiles
    // 0..31 land on XCD0, etc. Speed-only (L2 locality), not correctness.
    int blk = ((blockIdx.x & 7) << 5) | (blockIdx.x >> 3);
    int b = blk >> 6;
    int tid = threadIdx.x;
    int w = tid >> 6, lane = tid & 63;

    __shared__ __align__(16) unsigned lmask[2][HH][8];   // 16 KB (full, for fallback)
    __shared__ unsigned wfl[16];
    __shared__ float wsum[16];
    __shared__ double dsum[4];

    // prefetch this thread's query pixels: latency hides under the build
    int x = tid & (WW - 1);
    int y0 = (blk & 63) << 2;
    int yq = y0 + (tid >> 8);                 // wave-uniform row of the 4-row tile
    int idx = (b * HH + yq) * WW + x;
    float pv = pred[idx], tv = tgt[idx];

    // ---- Local window build: rows [y0-SMAX, y0+3+SMAX] clamped, both images.
    // <= 40 rows -> <= 3 iters/wave; 8 lanes store the row's 8 words.
    int ylo = y0 - SMAX; if (ylo < 0) ylo = 0;
    int yhi = y0 + 3 + SMAX; if (yhi > HH - 1) yhi = HH - 1;
    int nrows = yhi - ylo + 1;
    int tot = nrows * 2;
    #pragma unroll 2
    for (int i = w; i < tot; i += 16) {
        int img = (i >= nrows) ? 1 : 0;
        int y = ylo + (img ? i - nrows : i);
        const float* rowp = (img ? tgt : pred) + (b * HH + y) * WW;
        unsigned v;
        PACK_ROW(rowp, v);
        if ((lane & 7) == 0) lmask[img][y][lane >> 3] = v;
    }
    __syncthreads();

    // ---- Fast path: fused truncated col_min on the local window.
    unsigned ivp = (pv > 0.5f) ? 0xFFFFFFFFu : 0u;
    unsigned ivt = (tv > 0.5f) ? 0xFFFFFFFFu : 0u;
    float bp, bt;
    col_min2_win(&lmask[0][0][0], &lmask[1][0][0], yq, x, ivp, ivt, bp, bt);
    bool conv_p = (bp <= CONV_T), conv_t = (bt <= CONV_T);
    float d2p = 0.0f, d2t = 0.0f;
    if (conv_p) { float dt = sqrtf(fminf(bp, BIGF)); d2p = dt * dt; }
    if (conv_t) { float dt = sqrtf(fminf(bt, BIGF)); d2t = dt * dt; }

    // block-uniform fallback decision
    unsigned long long fb = __ballot(!(conv_p && conv_t));
    if ((tid & 63) == 0) wfl[w] = (fb != 0ULL) ? 1u : 0u;
    __syncthreads();
    unsigned fb_any = wfl[0] | wfl[1] | wfl[2] | wfl[3] | wfl[4] | wfl[5] | wfl[6]
                    | wfl[7] | wfl[8] | wfl[9] | wfl[10] | wfl[11] | wfl[12]
                    | wfl[13] | wfl[14] | wfl[15];

    if (fb_any) {
        // ---- Fallback (pathological masks only): LOCAL full rebuild of both
        // images' 256-row masks (no inter-block traffic), then exact full-range
        // col_min for unconverged threads with fg-any gating.
        __syncthreads();              // all waves past wfl read / lmask fast-path reads
        unsigned any0 = 0u, any1 = 0u;
        #pragma unroll 4
        for (int i = w; i < 512; i += 16) {   // 32 rows/wave
            int img = i >> 8, y = i & 255;
            const float* rowp = (img ? tgt : pred) + (b * HH + y) * WW;
            unsigned v;
            PACK_ROW(rowp, v);
            if (img) any1 |= v; else any0 |= v;
            if ((lane & 7) == 0) lmask[img][y][lane >> 3] = v;
        }
        unsigned long long A0 = __ballot(any0 != 0u);
        unsigned long long A1 = __ballot(any1 != 0u);
        if (lane == 0) wfl[w] = (A0 ? 1u : 0u) | (A1 ? 2u : 0u);
        __syncthreads();
        unsigned m = wfl[0] | wfl[1] | wfl[2] | wfl[3] | wfl[4] | wfl[5] | wfl[6]
                   | wfl[7] | wfl[8] | wfl[9] | wfl[10] | wfl[11] | wfl[12]
                   | wfl[13] | wfl[14] | wfl[15];
        unsigned fl_p = m & 1u, fl_t = m & 2u;
        if (!conv_p) {
            d2p = 0.0f;
            if (fl_p) {
                float best = col_min(&lmask[0][0][0], yq, x, ivp);
                float dt = sqrtf(fminf(best, BIGF));
                d2p = dt * dt;
            }
        }
        if (!conv_t) {
            d2t = 0.0f;
            if (fl_t) {
                float best = col_min(&lmask[1][0][0], yq, x, ivt);
                float dt = sqrtf(fminf(best, BIGF));
                d2t = dt * dt;
            }
        }
    }

    float e = pv - tv;
    float lsum = (e * e) * (d2p + d2t);

    // block reduce: wave64 shuffle then LDS across 16 waves
    #pragma unroll
    for (int off = 32; off > 0; off >>= 1)
        lsum += __shfl_down(lsum, off, 64);
    if ((tid & 63) == 0) wsum[tid >> 6] = lsum;
    __syncthreads();

    // ---- Atomic-free tail: publish partial, then block 0 reduces all 256.
    if (tid == 0) {
        float s2 = 0.0f;
        #pragma unroll
        for (int i = 0; i < 16; ++i) s2 += wsum[i];
        STORE_RLX(&accb[blk], (unsigned long long)__double_as_longlong((double)s2));
        asm volatile("s_waitcnt vmcnt(0)" ::: "memory");  // partial ACKed before flag
        STORE_RLX(&done[blk], MAGIC);
    }
    if (blk == 0) {   // waits only on others' COMPLETED work; nobody waits on blk 0
        double v = 0.0;
        if (tid < GRID) {
            while (LOAD_RLX(&done[tid]) != MAGIC)
                __builtin_amdgcn_s_sleep(1);
            v = __longlong_as_double((long long)LOAD_RLX(&accb[tid]));
        }
        #pragma unroll
        for (int off = 32; off > 0; off >>= 1)
            v += __shfl_down(v, off, 64);
        if (tid < GRID && (tid & 63) == 0) dsum[tid >> 6] = v;
        __syncthreads();
        if (tid == 0)
            out[0] = (float)((dsum[0] + dsum[1] + dsum[2] + dsum[3])
                             * (1.0 / (double)NPIX));
    }
}

extern "C" void kernel_launch(void* const* d_in, const int* in_sizes, int n_in,
                              void* d_out, int out_size, void* d_ws, size_t ws_size,
                              hipStream_t stream) {
    const float* pred = (const float*)d_in[0];
    const float* tgt = (const float*)d_in[1];
    float* out = (float*)d_out;
    char* ws = (char*)d_ws;
    unsigned long long* accb = (unsigned long long*)(ws + WS_ACCB_OFF);
    unsigned* done = (unsigned*)(ws + WS_DONE_OFF);

    hdt_kernel<<<GRID, 1024, 0, stream>>>(pred, tgt, done, accb, out);
}

// Round 9
// 59.551 us; speedup vs baseline: 1.2674x; 1.0260x over previous
//
#include <hip/hip_runtime.h>

#define BIGF 1e10f
#define HH 256
#define WW 256
#define BB 4
#define NPIX (BB * HH * WW)
#define GRID 256            // == #CUs: 1 block/CU
#define MAGIC 0x5F3A9C71u   // multi-byte value: cannot alias a byte-pattern ws poison
#define SMAX 4              // local column window; exact iff best <= (SMAX+1)^2
#define CONV_T 25.0f        // (SMAX+1)^2

// ws layout (bytes):
//   [0 .. 2047]     u64 accb[256] : per-block double partial sums (bit pattern)
//   [3072 .. 4095]  u32 done[256] : partial-sum-published flags
// NO workspace init needed: accb is read only after done==MAGIC.
#define WS_ACCB_OFF 0
#define WS_DONE_OFF 3072

#define LOAD_RLX(p)     __hip_atomic_load((p), __ATOMIC_RELAXED, __HIP_MEMORY_SCOPE_AGENT)
#define STORE_RLX(p, v) __hip_atomic_store((p), (v), __ATOMIC_RELAXED, __HIP_MEMORY_SCOPE_AGENT)

// Exact 1D distance^2 along a row to the nearest bit of class (mask ^ iv),
// from position x. 8 u32 words per row in LDS; near-uniform addresses per wave.
__device__ inline float row_d2(const unsigned* __restrict__ rm, int x, unsigned iv) {
    int wx = x >> 5, bx = x & 31;
    int dl = 1 << 20, dr = 1 << 20;
    unsigned m0 = rm[wx] ^ iv;                    // shared by both directions
    unsigned t = m0 & (0xFFFFFFFFu >> (31 - bx)); // bits <= bx
    int w = wx;
    while (true) {
        if (t) { int p = (w << 5) + 31 - __builtin_clz(t); dl = x - p; break; }
        if (--w < 0) break;
        t = rm[w] ^ iv;
    }
    t = m0 & (0xFFFFFFFFu << bx);                 // bits >= bx
    w = wx;
    while (true) {
        if (t) { int p = (w << 5) + __builtin_ctz(t); dr = p - x; break; }
        if (++w > 7) break;
        t = rm[w] ^ iv;
    }
    int d = dl < dr ? dl : dr;
    return (d > 255) ? BIGF : (float)(d * d);
}

// Exact expanding-window min-plus along the column (full range, fallback path).
__device__ inline float col_min(const unsigned* __restrict__ mb, int y, int x, unsigned iv) {
    float best = row_d2(mb + y * 8, x, iv);
    #pragma unroll 1
    for (int s = 1; s < HH; ++s) {
        float ss = (float)(s * s);
        if (ss >= best) break;
        int ym = y - s, yp = y + s;
        if (ym >= 0) best = fminf(best, row_d2(mb + ym * 8, x, iv) + ss);
        if (yp < HH) best = fminf(best, row_d2(mb + yp * 8, x, iv) + ss);
    }
    return best;
}

// Fused truncated variant: both images in ONE s-loop (2x ILP on the dependent
// LDS-scan chain). Per-image iterations are identical to the full loop while
// s <= SMAX; result exact iff it converged (best <= (SMAX+1)^2: any s>SMAX
// candidate costs >= that, and the full loop breaks on ss >= best).
__device__ inline void col_min2_win(const unsigned* __restrict__ mb0,
                                    const unsigned* __restrict__ mb1,
                                    int y, int x, unsigned iv0, unsigned iv1,
                                    float& b0, float& b1) {
    b0 = row_d2(mb0 + y * 8, x, iv0);
    b1 = row_d2(mb1 + y * 8, x, iv1);
    #pragma unroll 1
    for (int s = 1; s <= SMAX; ++s) {
        float ss = (float)(s * s);
        bool d0 = (ss >= b0), d1 = (ss >= b1);
        if (d0 && d1) break;
        int ym = y - s, yp = y + s;
        if (!d0) {
            if (ym >= 0) b0 = fminf(b0, row_d2(mb0 + ym * 8, x, iv0) + ss);
            if (yp < HH) b0 = fminf(b0, row_d2(mb0 + yp * 8, x, iv0) + ss);
        }
        if (!d1) {
            if (ym >= 0) b1 = fminf(b1, row_d2(mb1 + ym * 8, x, iv1) + ss);
            if (yp < HH) b1 = fminf(b1, row_d2(mb1 + yp * 8, x, iv1) + ss);
        }
    }
}

// pack one row's 256 pixels into 8 mask words: float4/lane + nibble + shfl OR-tree
#define PACK_ROW(rowp, vout)                                                  \
    {                                                                         \
        const float4 f = ((const float4*)(rowp))[lane];                       \
        unsigned nib = (f.x > 0.5f ? 1u : 0u) | (f.y > 0.5f ? 2u : 0u)        \
                     | (f.z > 0.5f ? 4u : 0u) | (f.w > 0.5f ? 8u : 0u);       \
        vout = nib << ((lane & 7) << 2);                                      \
        vout |= __shfl_xor(vout, 1, 64);                                      \
        vout |= __shfl_xor(vout, 2, 64);                                      \
        vout |= __shfl_xor(vout, 4, 64);                                      \
    }

// Fully self-sufficient kernel: NO inter-block mask traffic.
// Fast path: local +-SMAX window build + fused truncated col_min (exact when
// converged; convergence implies fg-any), ONE barrier for ballot+reduce.
// Rare fallback (sparse/empty masks): block rebuilds the FULL 512-row mask set
// locally and recomputes unconverged threads with fg-any gating.
// Tail: atomic-free store+flag, block 0 reduces. XCD-chunked tile map.
__launch_bounds__(1024, 4)
__global__ void hdt_kernel(const float* __restrict__ pred,
                           const float* __restrict__ tgt,
                           unsigned* __restrict__ done,
                           unsigned long long* __restrict__ accb,
                           float* __restrict__ out) {
    // XCD-aware swizzle: blockIdx round-robins XCDs; chunk so logical tiles
    // 0..31 land on XCD0, etc. Speed-only (L2 locality), not correctness.
    int blk = ((blockIdx.x & 7) << 5) | (blockIdx.x >> 3);
    int b = blk >> 6;
    int tid = threadIdx.x;
    int w = tid >> 6, lane = tid & 63;

    __shared__ __align__(16) unsigned lmask[2][HH][8];   // 16 KB (full, for fallback)
    __shared__ unsigned wfl[16];
    __shared__ float wsum[16];
    __shared__ double dsum[4];

    // prefetch this thread's query pixels: latency hides under the build
    int x = tid & (WW - 1);
    int y0 = (blk & 63) << 2;
    int yq = y0 + (tid >> 8);                 // wave-uniform row of the 4-row tile
    int idx = (b * HH + yq) * WW + x;
    float pv = pred[idx], tv = tgt[idx];

    // ---- Local window build: rows [y0-SMAX, y0+3+SMAX] clamped, both images.
    // <= 24 row-builds: waves 0-7 do 2, waves 8-15 do 1.
    int ylo = y0 - SMAX; if (ylo < 0) ylo = 0;
    int yhi = y0 + 3 + SMAX; if (yhi > HH - 1) yhi = HH - 1;
    int nrows = yhi - ylo + 1;
    int tot = nrows * 2;
    #pragma unroll 2
    for (int i = w; i < tot; i += 16) {
        int img = (i >= nrows) ? 1 : 0;
        int y = ylo + (img ? i - nrows : i);
        const float* rowp = (img ? tgt : pred) + (b * HH + y) * WW;
        unsigned v;
        PACK_ROW(rowp, v);
        if ((lane & 7) == 0) lmask[img][y][lane >> 3] = v;
    }
    __syncthreads();

    // ---- Fast path: fused truncated col_min on the local window.
    unsigned ivp = (pv > 0.5f) ? 0xFFFFFFFFu : 0u;
    unsigned ivt = (tv > 0.5f) ? 0xFFFFFFFFu : 0u;
    float bp, bt;
    col_min2_win(&lmask[0][0][0], &lmask[1][0][0], yq, x, ivp, ivt, bp, bt);
    bool conv_p = (bp <= CONV_T), conv_t = (bt <= CONV_T);
    float d2p = 0.0f, d2t = 0.0f;
    if (conv_p) { float dt = sqrtf(fminf(bp, BIGF)); d2p = dt * dt; }
    if (conv_t) { float dt = sqrtf(fminf(bt, BIGF)); d2t = dt * dt; }

    float e = pv - tv;
    float errsq = e * e;
    float lsum = errsq * (d2p + d2t);

    // ---- Single-barrier ballot + reduce: wave64 shuffle reduce, then wsum[w]
    // and the fallback flag wfl[w] published in the same LDS round trip.
    unsigned long long fb = __ballot(!(conv_p && conv_t));
    #pragma unroll
    for (int off = 32; off > 0; off >>= 1)
        lsum += __shfl_down(lsum, off, 64);
    if (lane == 0) { wsum[w] = lsum; wfl[w] = (fb != 0ULL) ? 1u : 0u; }
    __syncthreads();
    unsigned fb_any = wfl[0] | wfl[1] | wfl[2] | wfl[3] | wfl[4] | wfl[5] | wfl[6]
                    | wfl[7] | wfl[8] | wfl[9] | wfl[10] | wfl[11] | wfl[12]
                    | wfl[13] | wfl[14] | wfl[15];

    if (fb_any) {
        // ---- Fallback (pathological masks only): LOCAL full rebuild of both
        // images' 256-row masks (no inter-block traffic), then exact full-range
        // col_min for unconverged threads with fg-any gating.
        __syncthreads();              // all waves done reading wfl / fast-path lmask
        unsigned any0 = 0u, any1 = 0u;
        #pragma unroll 4
        for (int i = w; i < 512; i += 16) {   // 32 rows/wave
            int img = i >> 8, y = i & 255;
            const float* rowp = (img ? tgt : pred) + (b * HH + y) * WW;
            unsigned v;
            PACK_ROW(rowp, v);
            if (img) any1 |= v; else any0 |= v;
            if ((lane & 7) == 0) lmask[img][y][lane >> 3] = v;
        }
        unsigned long long A0 = __ballot(any0 != 0u);
        unsigned long long A1 = __ballot(any1 != 0u);
        if (lane == 0) wfl[w] = (A0 ? 1u : 0u) | (A1 ? 2u : 0u);
        __syncthreads();
        unsigned m = wfl[0] | wfl[1] | wfl[2] | wfl[3] | wfl[4] | wfl[5] | wfl[6]
                   | wfl[7] | wfl[8] | wfl[9] | wfl[10] | wfl[11] | wfl[12]
                   | wfl[13] | wfl[14] | wfl[15];
        unsigned fl_p = m & 1u, fl_t = m & 2u;
        if (!conv_p) {
            d2p = 0.0f;
            if (fl_p) {
                float best = col_min(&lmask[0][0][0], yq, x, ivp);
                float dt = sqrtf(fminf(best, BIGF));
                d2p = dt * dt;
            }
        }
        if (!conv_t) {
            d2t = 0.0f;
            if (fl_t) {
                float best = col_min(&lmask[1][0][0], yq, x, ivt);
                float dt = sqrtf(fminf(best, BIGF));
                d2t = dt * dt;
            }
        }
        // redo the block reduce with corrected values
        float ls = errsq * (d2p + d2t);
        #pragma unroll
        for (int off = 32; off > 0; off >>= 1)
            ls += __shfl_down(ls, off, 64);
        if (lane == 0) wsum[w] = ls;
        __syncthreads();
    }

    // ---- Atomic-free tail: publish partial, then block 0 reduces all 256.
    if (tid == 0) {
        float s2 = 0.0f;
        #pragma unroll
        for (int i = 0; i < 16; ++i) s2 += wsum[i];
        STORE_RLX(&accb[blk], (unsigned long long)__double_as_longlong((double)s2));
        asm volatile("s_waitcnt vmcnt(0)" ::: "memory");  // partial ACKed before flag
        STORE_RLX(&done[blk], MAGIC);
    }
    if (blk == 0) {   // waits only on others' COMPLETED work; nobody waits on blk 0
        double v = 0.0;
        if (tid < GRID) {
            while (LOAD_RLX(&done[tid]) != MAGIC)
                __builtin_amdgcn_s_sleep(1);
            v = __longlong_as_double((long long)LOAD_RLX(&accb[tid]));
        }
        #pragma unroll
        for (int off = 32; off > 0; off >>= 1)
            v += __shfl_down(v, off, 64);
        if (tid < GRID && (tid & 63) == 0) dsum[tid >> 6] = v;
        __syncthreads();
        if (tid == 0)
            out[0] = (float)((dsum[0] + dsum[1] + dsum[2] + dsum[3])
                             * (1.0 / (double)NPIX));
    }
}

extern "C" void kernel_launch(void* const* d_in, const int* in_sizes, int n_in,
                              void* d_out, int out_size, void* d_ws, size_t ws_size,
                              hipStream_t stream) {
    const float* pred = (const float*)d_in[0];
    const float* tgt = (const float*)d_in[1];
    float* out = (float*)d_out;
    char* ws = (char*)d_ws;
    unsigned long long* accb = (unsigned long long*)(ws + WS_ACCB_OFF);
    unsigned* done = (unsigned*)(ws + WS_DONE_OFF);

    hdt_kernel<<<GRID, 1024, 0, stream>>>(pred, tgt, done, accb, out);
}